// Round 15
// baseline (482.937 us; speedup 1.0000x reference)
//
#include <hip/hip_runtime.h>
#include <hip/hip_bf16.h>
#include <math.h>

// ---------------------------------------------------------------------------
// Quantized CNN forward (bitwise-exact vs fp32 reference):
//   block_k: maxpool2( quant_act( conv3x3(x, quant_weight(wk)), ak ) )
//   then global max over HxW, then 1x1 conv (10x128).
// Sparse formulation (R7+, absmax 0.0): ternary weights ~96% zero; skipping
// all-zero (co,ci) pairs is bitwise-safe; per-co accumulation (ci asc, k asc).
//
// R15: R14's staging pipeline confirmed staging as the wall (577->477).
// Remaining waste: every co-group re-stages the same input tile (conv2 x4,
// conv3 x8), 20 loads + 20 ds_writes per thread-chunk. This round merges all
// co-groups into one block: 4 waves over an 8x8 POOLED tile (64 lanes = 64
// pixels), each WAVE owns a 16-co slice. Input tile shrinks to 18x18 (324
// words/ci): staging per thread-chunk drops to 8+8 (3.6x less), FETCH drops,
// LDS -> 5.2KB. Compute bodies identical to R14 (mask-guarded dense 36-FMA,
// scalar coefs via readfirstlane(slice)); order unchanged -> absmax 0.0.
// ---------------------------------------------------------------------------

__global__ __launch_bounds__(64)
void prep_zero(unsigned* __restrict__ maxb) {
    if (threadIdx.x < 4) maxb[threadIdx.x] = 0u;
}

__global__ __launch_bounds__(256)
void prep_absmax(const float* __restrict__ w1, const float* __restrict__ w2,
                 const float* __restrict__ w3, const float* __restrict__ wc,
                 unsigned* __restrict__ maxb) {
    const float* srcs[4] = {w1, w2, w3, wc};
    const int    ns[4]   = {32*3*9, 64*32*9, 128*64*9, 10*128};
    const int t = blockIdx.y;
    const float* s = srcs[t];
    const int    N = ns[t];
    float m = 0.f;
    for (int i = blockIdx.x * 256 + threadIdx.x; i < N; i += 16 * 256)
        m = fmaxf(m, fabsf(s[i]));
    #pragma unroll
    for (int o = 32; o > 0; o >>= 1) m = fmaxf(m, __shfl_down(m, o));
    __shared__ float red[4];
    const int lane = threadIdx.x & 63, wid = threadIdx.x >> 6;
    if (lane == 0) red[wid] = m;
    __syncthreads();
    if (threadIdx.x == 0) {
        float mm = fmaxf(fmaxf(red[0], red[1]), fmaxf(red[2], red[3]));
        atomicMax(maxb + t, __float_as_uint(mm));  // |w|>=0: uint order == float order
    }
}

__global__ __launch_bounds__(256)
void prep_quant(const float* __restrict__ w1, const float* __restrict__ w2,
                const float* __restrict__ w3, const float* __restrict__ wc,
                const unsigned* __restrict__ maxb,
                float* __restrict__ q1, float* __restrict__ q2,
                float* __restrict__ q3, float* __restrict__ qc) {
    const float* srcs[4] = {w1, w2, w3, wc};
    float*       dsts[4] = {q1, q2, q3, qc};
    const int    ns[4]   = {32*3*9, 64*32*9, 128*64*9, 10*128};
    const int t = blockIdx.y;
    const float* s = srcs[t];
    float*       d = dsts[t];
    const int    N = ns[t];
    const float sc = fmaxf(__uint_as_float(maxb[t]), 1e-8f);  // qmax = 2^(2-1)-1 = 1
    for (int i = blockIdx.x * 256 + threadIdx.x; i < N; i += 16 * 256)
        d[i] = rintf(s[i] / sc) * sc;
}

// Build (a) 64-bit pair masks per (co-slice-of-NCOW, ci-chunk-of-4): bit
// (cil*16 + c) set iff pair (co=slice*NCOW+c, ci=chunk*4+cil) has a nonzero;
// (b) padded coef table cw: 12-float (16B-aligned) rows,
// row = ((slice*nchunk+chunk)*4 + cil)*16 + c, coefs k=0..8 then 3 zeros.
__global__ __launch_bounds__(256)
void build_masks(const float* __restrict__ qw, int Co, int CIN, int NCOW,
                 unsigned* __restrict__ masks, float* __restrict__ cw) {
    const int nchunk = (CIN + 3) / 4;
    const int nslice = Co / NCOW;
    const int ndw = nslice * nchunk * 2;
    const int t = threadIdx.x;
    for (int i = t; i < ndw; i += 256) {
        const int row = i >> 1, d = i & 1;
        const int sl = row / nchunk, ch = row - sl * nchunk;
        unsigned m = 0;
        for (int bit = 0; bit < 32; ++bit) {
            const int lin = d * 32 + bit;          // cil*16 + c
            const int cil = lin >> 4, c = lin & 15;
            const int ci = ch * 4 + cil, co = sl * NCOW + c;
            if (ci < CIN && c < NCOW) {
                bool nz = false;
                for (int k = 0; k < 9; ++k)
                    nz |= (qw[(co * CIN + ci) * 9 + k] != 0.f);
                if (nz) m |= (1u << bit);
            }
        }
        masks[i] = m;
    }
    const int npair = nslice * nchunk * 4 * 16;
    for (int pidx = t; pidx < npair; pidx += 256) {
        const int c = pidx & 15, rest = pidx >> 4;
        const int cil = rest & 3, row2 = rest >> 2;
        const int sl = row2 / nchunk, ch = row2 - sl * nchunk;
        const int ci = ch * 4 + cil, co = sl * NCOW + c;
        float* dst = cw + (size_t)pidx * 12;
        #pragma unroll
        for (int k = 0; k < 9; ++k)
            dst[k] = (ci < CIN && c < NCOW) ? qw[(co * CIN + ci) * 9 + k] : 0.f;
        dst[9] = dst[10] = dst[11] = 0.f;
    }
}

// Sparse fused conv3x3(pad=1) + maxpool2 + quant_act.
// Block = 4 waves over an 8x8 POOLED tile (lane = py_l*8+px_l); each wave
// owns a NCOW co-slice. Input tile 18x18 (324 words) per ci, chunks of 4 ci,
// register-pipelined staging (R14), mask-guarded dense 36-FMA bodies (R12).
template<int CIN, int Co, int NCOW>
__global__ __launch_bounds__(256, 4)
void conv_sparse(const float* __restrict__ in, const unsigned* __restrict__ masks,
                 const float* __restrict__ cw,
                 const float* __restrict__ alpha_p, float* __restrict__ out,
                 int H, int W) {
    constexpr int NCHUNK = (CIN + 3) / 4;
    constexpr int CCH    = (CIN < 4) ? CIN : 4;
    constexpr int NG     = Co / (NCOW * 4);      // co-group blocks
    const int PH = H >> 1, PW = W >> 1;
    const int tid  = threadIdx.x;
    const int wv   = tid >> 6, lane = tid & 63;
    const int px_l = lane & 7, py_l = lane >> 3;
    const int b    = blockIdx.z / NG;
    const int zg   = blockIdx.z % NG;
    const int slice = __builtin_amdgcn_readfirstlane(zg * 4 + wv);  // scalar
    const int px  = blockIdx.x * 8 + px_l;
    const int py  = blockIdx.y * 8 + py_l;
    const int ix0 = blockIdx.x * 16 - 1;
    const int iy0 = blockIdx.y * 16 - 1;

    __shared__ float tile[CCH * 324];            // chunk-local [cil][18*18] flat
    const size_t HW = (size_t)H * W;
    const float* inB = in + (size_t)b * CIN * HW;

    // Flat staging slots hoisted once; -1 = zero-fill (pad / out of image).
    int sidx[2];
    #pragma unroll
    for (int s = 0; s < 2; ++s) {
        const int idx = tid + 256 * s;
        const int r = idx / 18, c = idx - r * 18;
        const int gy = iy0 + r, gx = ix0 + c;
        sidx[s] = (idx < 324 && gy >= 0 && gy < H && gx >= 0 && gx < W)
                  ? (gy * W + gx) : -1;
    }

    float v[CCH][2];                              // in-flight staging buffer
    auto load_chunk = [&](int ch0) {
        #pragma unroll
        for (int ch = 0; ch < CCH; ++ch) {
            const float* inC = inB + (size_t)(ch0 + ch) * HW;
            #pragma unroll
            for (int s = 0; s < 2; ++s)
                v[ch][s] = (sidx[s] >= 0) ? inC[sidx[s]] : 0.f;
        }
    };
    auto store_tile = [&]() {
        #pragma unroll
        for (int ch = 0; ch < CCH; ++ch)
            #pragma unroll
            for (int s = 0; s < 2; ++s) {
                const int idx = tid + 256 * s;    // imm-offset ds_write
                if (s < 1 || idx < 324) tile[ch * 324 + idx] = v[ch][s];
            }
    };

    float acc[NCOW][4];
    #pragma unroll
    for (int c = 0; c < NCOW; ++c)
        #pragma unroll
        for (int q = 0; q < 4; ++q) acc[c][q] = 0.f;

    const int base = (2 * py_l) * 18 + 2 * px_l; // even -> b64-aligned reads

    load_chunk(0);                                // prologue

    #pragma unroll 1
    for (int chunk = 0; chunk < NCHUNK; ++chunk) {
        __syncthreads();                          // tile free (prev compute done)
        store_tile();                             // v holds this chunk (aged)
        if (chunk + 1 < NCHUNK) load_chunk((chunk + 1) * 4);  // issue early
        __syncthreads();                          // writes visible

        // 64-bit pair mask for (slice, chunk) -> scalar regs.
        const unsigned* mp = masks + (size_t)(slice * NCHUNK + chunk) * 2;
        const unsigned mv0 = mp[0], mv1 = mp[1];

        const float* cwc = cw + (size_t)((slice * NCHUNK + chunk) * 4) * 16 * 12;

        #pragma unroll 1
        for (int cil = 0; cil < CCH; ++cil) {
            const unsigned m16 =
                ((cil & 2 ? mv1 : mv0) >> ((cil & 1) * 16)) & 0xffffu;
            if (!m16) continue;

            // Dense 4x4 patch: all nine k-stencils for the 2x2 outputs.
            float p[4][4];
            const float* tb = tile + cil * 324 + base;
            #pragma unroll
            for (int r = 0; r < 4; ++r) {
                const float2 a  = *(const float2*)&tb[r * 18];
                const float2 c2 = *(const float2*)&tb[r * 18 + 2];
                p[r][0] = a.x; p[r][1] = a.y; p[r][2] = c2.x; p[r][3] = c2.y;
            }

            const float* cwr = cwc + (size_t)cil * 16 * 12;
            #pragma unroll
            for (int c = 0; c < NCOW; ++c) {
                if (m16 & (1u << c)) {            // uniform s_bitcmp+s_cbranch
                    const float* wp = cwr + c * 12;   // 16B-aligned row
                    #pragma unroll
                    for (int k = 0; k < 9; ++k) {
                        const float w = wp[k];        // uniform -> s_load
                        acc[c][0] = fmaf(w, p[k/3    ][k%3    ], acc[c][0]);
                        acc[c][1] = fmaf(w, p[k/3    ][k%3 + 1], acc[c][1]);
                        acc[c][2] = fmaf(w, p[k/3 + 1][k%3    ], acc[c][2]);
                        acc[c][3] = fmaf(w, p[k/3 + 1][k%3 + 1], acc[c][3]);
                    }
                }
            }
        }
    }

    if (py < PH && px < PW) {
        const float alpha = *alpha_p;
        const float scale = alpha / 3.0f;         // 2^ABITS - 1 = 3
        const int co0 = slice * NCOW;
        #pragma unroll
        for (int c = 0; c < NCOW; ++c) {
            const float m = fmaxf(fmaxf(acc[c][0], acc[c][1]),
                                  fmaxf(acc[c][2], acc[c][3]));
            const float y = fminf(fmaxf(m, 0.f), alpha);
            out[(((size_t)b * Co + co0 + c) * PH + py) * PW + px] =
                rintf(y / scale) * scale;
        }
    }
}

// One wave per (channel, batch): global max over 28x28.
__global__ __launch_bounds__(64)
void gmax_kernel(const float* __restrict__ h3, float* __restrict__ g) {
    const int c = blockIdx.x, b = blockIdx.y;
    const float* p = h3 + ((size_t)b * 128 + c) * 784;
    float m = -INFINITY;
    for (int i = threadIdx.x; i < 784; i += 64) m = fmaxf(m, p[i]);
    #pragma unroll
    for (int o = 32; o > 0; o >>= 1) m = fmaxf(m, __shfl_down(m, o));
    if (threadIdx.x == 0) g[b * 128 + c] = m;
}

// 1x1 conv 128->10 per batch (same k-ascending FMA order as round 1).
__global__ __launch_bounds__(128)
void classify_kernel(const float* __restrict__ g, const float* __restrict__ qwc,
                     float* __restrict__ out) {
    const int b = blockIdx.x;
    __shared__ float gg[128];
    gg[threadIdx.x] = g[b * 128 + threadIdx.x];
    __syncthreads();
    if (threadIdx.x < 10) {
        float s = 0.f;
        for (int k = 0; k < 128; ++k) s += qwc[threadIdx.x * 128 + k] * gg[k];
        out[b * 10 + threadIdx.x] = s;
    }
}

extern "C" void kernel_launch(void* const* d_in, const int* in_sizes, int n_in,
                              void* d_out, int out_size, void* d_ws, size_t ws_size,
                              hipStream_t stream) {
    const float* x  = (const float*)d_in[0];
    const float* w1 = (const float*)d_in[1];
    const float* w2 = (const float*)d_in[2];
    const float* w3 = (const float*)d_in[3];
    const float* wc = (const float*)d_in[4];
    const float* a1 = (const float*)d_in[5];
    const float* a2 = (const float*)d_in[6];
    const float* a3 = (const float*)d_in[7];

    float* ws = (float*)d_ws;
    size_t o = 0;
    float* qw1 = ws + o; o += 32 * 3 * 9;           // 864
    float* qw2 = ws + o; o += 64 * 32 * 9;          // 18432
    float* qw3 = ws + o; o += 128 * 64 * 9;         // 73728
    float* qwc = ws + o; o += 10 * 128;             // 1280
    unsigned* maxb = (unsigned*)(ws + o); o += 4;
    float* g   = ws + o; o += 32 * 128;             // 4096
    unsigned* mk1 = (unsigned*)(ws + o); o += 8;    // 4 slice * 1 ch * 2
    unsigned* mk2 = (unsigned*)(ws + o); o += 64;   // 4 slice * 8 ch * 2
    unsigned* mk3 = (unsigned*)(ws + o); o += 256;  // 8 slice * 16 ch * 2
    float* cw1 = ws + o; o += 4UL * 1 * 4 * 16 * 12;    //  3072 (16B aligned)
    float* cw2 = ws + o; o += 4UL * 8 * 4 * 16 * 12;    // 24576
    float* cw3 = ws + o; o += 8UL * 16 * 4 * 16 * 12;   // 98304
    float* h1p = ws + o; o += 32UL * 32 * 112 * 112;
    float* h2p = ws + o; o += 32UL * 64 * 56 * 56;
    float* h3p = ws + o; o += 32UL * 128 * 28 * 28;

    prep_zero<<<1, 64, 0, stream>>>(maxb);
    prep_absmax<<<dim3(16, 4), 256, 0, stream>>>(w1, w2, w3, wc, maxb);
    prep_quant<<<dim3(16, 4), 256, 0, stream>>>(w1, w2, w3, wc, maxb,
                                                qw1, qw2, qw3, qwc);
    build_masks<<<1, 256, 0, stream>>>(qw1, 32, 3,  8,  mk1, cw1);
    build_masks<<<1, 256, 0, stream>>>(qw2, 64, 32, 16, mk2, cw2);
    build_masks<<<1, 256, 0, stream>>>(qw3, 128, 64, 16, mk3, cw3);

    // conv1: 3->32, 224x224 -> pooled 112x112. 14x14 tiles, NCOW=8, NG=1.
    conv_sparse<3, 32, 8><<<dim3(14, 14, 32), 256, 0, stream>>>(
        x, mk1, cw1, a1, h1p, 224, 224);
    // conv2: 32->64, pooled 56x56. 7x7 tiles, NCOW=16, NG=1.
    conv_sparse<32, 64, 16><<<dim3(7, 7, 32), 256, 0, stream>>>(
        h1p, mk2, cw2, a2, h2p, 112, 112);
    // conv3: 64->128, pooled 28x28. 4x4 tiles, NCOW=16, NG=2.
    conv_sparse<64, 128, 16><<<dim3(4, 4, 32 * 2), 256, 0, stream>>>(
        h2p, mk3, cw3, a3, h3p, 56, 56);

    gmax_kernel<<<dim3(128, 32), 64, 0, stream>>>(h3p, g);
    classify_kernel<<<32, 128, 0, stream>>>(g, qwc, (float*)d_out);
}